// Round 13
// baseline (248.306 us; speedup 1.0000x reference)
//
#include <hip/hip_runtime.h>
#include <hip/hip_bf16.h>

// ---------------- problem constants ----------------
#define LENQ 13294
#define MROWS 26588              // 2 * LENQ
#define PADM  26624              // 416 * 64 = 208 * 128
#define EPS_LN 1e-5f

typedef __attribute__((ext_vector_type(8))) short short8;
typedef __attribute__((ext_vector_type(4))) float vf4;
typedef __attribute__((ext_vector_type(2))) __bf16 bf16x2;

__device__ inline ushort f2bf(float f) {
    __hip_bfloat16 h = __float2bfloat16(f);
    return reinterpret_cast<ushort&>(h);
}
__device__ inline float bfbits2f(uint lo16) { return __uint_as_float(lo16 << 16); }
__device__ inline float lo16f(uint u) { return __uint_as_float(u << 16); }
__device__ inline float hi16f(uint u) { return __uint_as_float(u & 0xffff0000u); }

#if __has_builtin(__builtin_amdgcn_fdot2_f32_bf16) && __has_builtin(__builtin_amdgcn_perm)
#define USE_DOT2 1
__device__ inline bf16x2 u2bf2(uint u) { return __builtin_bit_cast(bf16x2, u); }
#define SEL_EVEN 0x01000504u
#define SEL_ODD  0x03020706u
#else
#define USE_DOT2 0
#endif

// async global->LDS, 16B per lane; LDS dest is wave-uniform base + lane*16
__device__ inline void load_lds16(const void* g, void* l) {
    __builtin_amdgcn_global_load_lds(
        (const __attribute__((address_space(1))) unsigned int*)g,
        (__attribute__((address_space(3))) unsigned int*)l,
        16, 0, 0);
}

// XCD-grouping block decode: all NT n-tiles of one m-panel land on the SAME XCD
// (bid % 8 == mt % 8 constant within the group) and are temporally adjacent,
// so the A-panel is fetched into that XCD's L2 once instead of NT times.
// Bijective when MT % 8 == 0.  [validated round 11: ~12 us on the GEMM cluster]
__device__ inline void xcd_decode(int bid, int NT, int& mt, int& nt) {
    const int xcd = bid & 7;
    const int rest = bid >> 3;
    nt = rest % NT;
    mt = (rest / NT) * 8 + xcd;
}

// ---------------- fused prep: all-weights convert+transpose AND src/q bf16 ----------------
__global__ __launch_bounds__(256) void prep_all(
    const float* __restrict__ Wv, const float* __restrict__ Woff,
    const float* __restrict__ Wattn, const float* __restrict__ Wout,
    const float* __restrict__ W1, const float* __restrict__ W2,
    ushort* __restrict__ wvt, ushort* __restrict__ woat,
    ushort* __restrict__ woutt, ushort* __restrict__ w1t, ushort* __restrict__ w2t,
    const float* __restrict__ srcf, const float* __restrict__ posf,
    ushort* __restrict__ srcb, ushort* __restrict__ qb)
{
    __shared__ float s[32][36];
    const int bid = blockIdx.x;
    const int t = threadIdx.x;
    if (bid < 736) {
        const float* src; ushort* dst; int K, N, tb;
        if      (bid < 64)  { src = Wv;    dst = wvt;            K = 256;  N = 256;  tb = bid; }
        else if (bid < 128) { src = Woff;  dst = woat;           K = 256;  N = 256;  tb = bid - 64; }
        else if (bid < 160) { src = Wattn; dst = woat + 256*256; K = 256;  N = 128;  tb = bid - 128; }
        else if (bid < 224) { src = Wout;  dst = woutt;          K = 256;  N = 256;  tb = bid - 160; }
        else if (bid < 480) { src = W1;    dst = w1t;            K = 256;  N = 1024; tb = bid - 224; }
        else                { src = W2;    dst = w2t;            K = 1024; N = 256;  tb = bid - 480; }
        const int ntn = N >> 5;
        const int kt = tb / ntn, nt = tb % ntn;
        const int ty = t >> 3, tx = (t & 7) * 4;
        float4 v = *reinterpret_cast<const float4*>(src + (size_t)(kt*32 + ty) * N + nt*32 + tx);
        s[ty][tx+0] = v.x; s[ty][tx+1] = v.y; s[ty][tx+2] = v.z; s[ty][tx+3] = v.w;
        __syncthreads();
        ushort4 o;
        o.x = f2bf(s[tx+0][ty]); o.y = f2bf(s[tx+1][ty]);
        o.z = f2bf(s[tx+2][ty]); o.w = f2bf(s[tx+3][ty]);
        *reinterpret_cast<ushort4*>(dst + (size_t)(nt*32 + ty) * K + kt*32 + tx) = o;
    } else {
        const int i = (bid - 736) * 256 + t;       // float4 index over PADM*64
        const int row = i >> 6;
        const int c4 = i & 63;
        const int sr = min(row, MROWS - 1);
        float4 sv = reinterpret_cast<const float4*>(srcf)[(size_t)sr * 64 + c4];
        float4 pv = reinterpret_cast<const float4*>(posf)[(size_t)sr * 64 + c4];
        ushort4 sb, qv;
        sb.x = f2bf(sv.x); sb.y = f2bf(sv.y); sb.z = f2bf(sv.z); sb.w = f2bf(sv.w);
        qv.x = f2bf(sv.x + pv.x); qv.y = f2bf(sv.y + pv.y);
        qv.z = f2bf(sv.z + pv.z); qv.w = f2bf(sv.w + pv.w);
        reinterpret_cast<ushort4*>(srcb)[(size_t)row * 64 + c4] = sb;
        reinterpret_cast<ushort4*>(qb)[(size_t)row * 64 + c4]   = qv;
    }
}

// ---------------- m97-style bf16 MFMA GEMM body, 2-phase prefetch (double-buffered) ----
// Tile BM x 128 (BM = MF*32), BK=32, 4 waves (2x2), global_load_lds staging.
template<int MF, bool RELU>
__device__ __forceinline__ void gemm_body(
    const ushort* __restrict__ A, const ushort* __restrict__ Bt,
    const float* __restrict__ bias0, const float* __restrict__ bias1, int nsplit,
    ushort* __restrict__ C, int N, int K, int m0, int n0,
    short* AsP, short* BsP)
{
    constexpr int BM = MF * 32;
    const int t = threadIdx.x;
    const int lane = t & 63, w = t >> 6;
    const int wr = w >> 1, wc = w & 1;
    const int ln = lane & 15, lr = lane >> 4;
    const int swz = (lr ^ ((ln >> 1) & 3)) * 8;
    const int cg = (((lane & 3) ^ ((lane >> 3) & 3))) * 8;
    const int srow = lane >> 2;

    vf4 acc[MF][4];
    #pragma unroll
    for (int m = 0; m < MF; ++m)
        #pragma unroll
        for (int n = 0; n < 4; ++n)
            acc[m][n] = (vf4){0.f, 0.f, 0.f, 0.f};

    const int ach0 = (MF == 4) ? 2 * w : w;
    const ushort* gA0 = A + (size_t)(m0 + ach0 * 16 + srow) * K + cg;
    const ushort* gA1 = A + (size_t)(m0 + (2 * w + 1) * 16 + srow) * K + cg;  // MF==4
    const ushort* gB0 = Bt + (size_t)(n0 + (2 * w) * 16 + srow) * K + cg;
    const ushort* gB1 = Bt + (size_t)(n0 + (2 * w + 1) * 16 + srow) * K + cg;
    const int lA0 = ach0 * 512, lA1 = (2 * w + 1) * 512;
    const int lB0 = (2 * w) * 512, lB1 = (2 * w + 1) * 512;

#define STAGE_TILE(buf, kk) do {                                              \
        load_lds16(gA0 + (kk), AsP + (buf) * (BM * 32) + lA0);                \
        if constexpr (MF == 4) load_lds16(gA1 + (kk), AsP + (buf) * (BM * 32) + lA1); \
        load_lds16(gB0 + (kk), BsP + (buf) * (128 * 32) + lB0);               \
        load_lds16(gB1 + (kk), BsP + (buf) * (128 * 32) + lB1);               \
    } while (0)

    STAGE_TILE(0, 0);
    int cur = 0;
    for (int k0 = 0; k0 < K; k0 += 32) {
        __syncthreads();
        if (k0 + 32 < K) STAGE_TILE(cur ^ 1, k0 + 32);

        short8 af[MF], bfr[4];
        #pragma unroll
        for (int m = 0; m < MF; ++m)
            af[m] = *reinterpret_cast<const short8*>(
                AsP + cur * (BM * 32) + (wr * (MF * 16) + m * 16 + ln) * 32 + swz);
        #pragma unroll
        for (int n = 0; n < 4; ++n)
            bfr[n] = *reinterpret_cast<const short8*>(
                BsP + cur * (128 * 32) + (wc * 64 + n * 16 + ln) * 32 + swz);
        #pragma unroll
        for (int m = 0; m < MF; ++m)
            #pragma unroll
            for (int n = 0; n < 4; ++n)
                acc[m][n] = __builtin_amdgcn_mfma_f32_16x16x32_bf16(af[m], bfr[n], acc[m][n], 0, 0, 0);
        cur ^= 1;
    }
#undef STAGE_TILE

    #pragma unroll
    for (int n = 0; n < 4; ++n) {
        const int col = n0 + wc * 64 + n * 16 + ln;
        const float b = (col < nsplit) ? bias0[col] : bias1[col - nsplit];
        #pragma unroll
        for (int m = 0; m < MF; ++m) {
            const int rbase = m0 + wr * (MF * 16) + m * 16 + lr * 4;
            #pragma unroll
            for (int q = 0; q < 4; ++q) {
                float v = acc[m][n][q] + b;
                if (RELU) v = fmaxf(v, 0.f);
                C[(size_t)(rbase + q) * N + col] = f2bf(v);
            }
        }
    }
}

// 1D grid, XCD-grouped; grid = (PADM/BM) * NT blocks
template<int MF, int NT, bool RELU>
__global__ __launch_bounds__(256) void gemm_single(
    const ushort* __restrict__ A, const ushort* __restrict__ Bt,
    const float* __restrict__ bias0, const float* __restrict__ bias1, int nsplit,
    ushort* __restrict__ C, int N, int K)
{
    constexpr int BM = MF * 32;
    __shared__ short As[2 * BM * 32];
    __shared__ short Bs[2 * 128 * 32];
    int mt, nt;
    xcd_decode(blockIdx.x, NT, mt, nt);
    gemm_body<MF, RELU>(A, Bt, bias0, bias1, nsplit, C, N, K,
                        mt * BM, nt * 128, As, Bs);
}

// value GEMM (nt<2) and [off|attn] GEMM (nt>=2) in one 1D launch, XCD-grouped (NT=5)
__global__ __launch_bounds__(256) void gemm_pair(
    const ushort* __restrict__ srcb, const ushort* __restrict__ wvt,
    const float* __restrict__ bv, ushort* __restrict__ valueb,
    const ushort* __restrict__ qb, const ushort* __restrict__ woat,
    const float* __restrict__ boff, const float* __restrict__ battn,
    ushort* __restrict__ oab)
{
    __shared__ short As[2 * 64 * 32];
    __shared__ short Bs[2 * 128 * 32];
    int mt, nt;
    xcd_decode(blockIdx.x, 5, mt, nt);
    if (nt < 2) {
        gemm_body<2, false>(srcb, wvt, bv, bv, 256, valueb, 256, 256,
                            mt * 64, nt * 128, As, Bs);
    } else {
        gemm_body<2, false>(qb, woat, boff, battn, 256, oab, 384, 256,
                            mt * 64, (nt - 2) * 128, As, Bs);
    }
}

// ---------------- fused softmax + multi-scale deformable sampling (bf16) ----------------
// 8 rows/block (r8 grid — best measured). Phase 1: per (r,h,lp) -> 4 byte-offsets +
// 2 bf16-pair weights -> LDS (SoA). Phase 2: 4 threads per (r,h), 8 channels each;
// BATCH-4 points: 16 independent gathers in flight per iteration (MLP for latency).
__global__ __launch_bounds__(256) void ms_sample(
    const ushort* __restrict__ value, const ushort* __restrict__ oa,
    const float* __restrict__ ref, ushort* __restrict__ outb)
{
    __shared__ uint s_off[64 * 68];   // 17408 B, group stride 68 uints
    __shared__ uint s_w[64 * 34];     // 8704 B, group stride 34 uints

    const int t    = threadIdx.x;
    const int row0 = blockIdx.x * 8;

    #pragma unroll
    for (int j = 0; j < 4; ++j) {
        const int item = t + j * 256;          // 0..1023
        const int r = item >> 7, h = (item >> 4) & 7, lp = item & 15;
        const int l = lp >> 2;
        const int row = min(row0 + r, MROWS - 1);
        const int bsel = (row >= LENQ) ? 1 : 0;

        const float lg = bfbits2f(oa[(size_t)row * 384 + 256 + h * 16 + lp]);
        float mx = lg;
        #pragma unroll
        for (int s2 = 1; s2 < 16; s2 <<= 1) mx = fmaxf(mx, __shfl_xor(mx, s2));
        const float e = __expf(lg - mx);
        float se = e;
        #pragma unroll
        for (int s2 = 1; s2 < 16; s2 <<= 1) se += __shfl_xor(se, s2);
        const float aw = e / se;

        const int W = (int)((0x0D193264u >> (l * 8)) & 0xffu);   // 100,50,25,13
        const int LS = (l == 0) ? 0 : (l == 1) ? 10000 : (l == 2) ? 12500 : 13125;
        const uint oxy = *reinterpret_cast<const uint*>(oa + (size_t)row * 384 + (h * 16 + lp) * 2);
        const float ox = lo16f(oxy);
        const float oy = hi16f(oxy);
        const float rx = ref[(size_t)row * 8 + l * 2 + 0];
        const float ry = ref[(size_t)row * 8 + l * 2 + 1];
        const float fw = (float)W;
        const float x = (rx + ox / fw) * fw - 0.5f;
        const float y = (ry + oy / fw) * fw - 0.5f;
        const float fx = floorf(x), fy = floorf(y);
        const float dx = x - fx, dy = y - fy;
        const int x0 = (int)fx, y0 = (int)fy;
        const int x1i = x0 + 1, y1i = y0 + 1;
        const int gbase = bsel * LENQ + LS;

        const bool inx0 = (x0 >= 0) && (x0 < W), inx1 = (x1i >= 0) && (x1i < W);
        const bool iny0 = (y0 >= 0) && (y0 < W), iny1 = (y1i >= 0) && (y1i < W);
        const int xc0 = min(max(x0, 0), W - 1), xc1 = min(max(x1i, 0), W - 1);
        const int yc0 = min(max(y0, 0), W - 1), yc1 = min(max(y1i, 0), W - 1);
        const float w00 = (inx0 && iny0) ? (1.f - dx) * (1.f - dy) * aw : 0.f;
        const float w10 = (inx1 && iny0) ? dx * (1.f - dy) * aw : 0.f;
        const float w01 = (inx0 && iny1) ? (1.f - dx) * dy * aw : 0.f;
        const float w11 = (inx1 && iny1) ? dx * dy * aw : 0.f;
        const uint b0 = (uint)(gbase + yc0 * W);
        const uint b1 = (uint)(gbase + yc1 * W);
        const int g = r * 8 + h;
        *reinterpret_cast<uint4*>(&s_off[g * 68 + lp * 4]) =
            make_uint4((b0 + (uint)xc0) * 512u, (b0 + (uint)xc1) * 512u,
                       (b1 + (uint)xc0) * 512u, (b1 + (uint)xc1) * 512u);
        const uint wA = (uint)f2bf(w00) | ((uint)f2bf(w10) << 16);
        const uint wB = (uint)f2bf(w01) | ((uint)f2bf(w11) << 16);
        *reinterpret_cast<uint2*>(&s_w[g * 34 + lp * 2]) = make_uint2(wA, wB);
    }
    __syncthreads();

    // phase 2: 4 threads per (r,h) group, 8 bf16 channels per thread.
    // 4 batches of 4 points; all 16 gathers of a batch issued before any use.
    const int g = t >> 2, cq = t & 3;
    const int h = g & 7;
    const char* vbase = (const char*)value + h * 64 + cq * 16;
    float acc[8] = {0.f, 0.f, 0.f, 0.f, 0.f, 0.f, 0.f, 0.f};

#if USE_DOT2
#define CORNER2(u0, u1, wpk, klo, khi)                                                 \
    acc[klo] = __builtin_amdgcn_fdot2_f32_bf16(                                        \
        u2bf2(__builtin_amdgcn_perm((u0), (u1), SEL_EVEN)), u2bf2(wpk), acc[klo], false); \
    acc[khi] = __builtin_amdgcn_fdot2_f32_bf16(                                        \
        u2bf2(__builtin_amdgcn_perm((u0), (u1), SEL_ODD)),  u2bf2(wpk), acc[khi], false);
#define POINT2(p00, p10, p01, p11, wp)                          \
    CORNER2(p00.x, p10.x, wp.x, 0, 1) CORNER2(p01.x, p11.x, wp.y, 0, 1) \
    CORNER2(p00.y, p10.y, wp.x, 2, 3) CORNER2(p01.y, p11.y, wp.y, 2, 3) \
    CORNER2(p00.z, p10.z, wp.x, 4, 5) CORNER2(p01.z, p11.z, wp.y, 4, 5) \
    CORNER2(p00.w, p10.w, wp.x, 6, 7) CORNER2(p01.w, p11.w, wp.y, 6, 7)
#else
#define CORNER1(gv, wf)                                                   \
    acc[0] += (wf) * lo16f(gv.x); acc[1] += (wf) * hi16f(gv.x);           \
    acc[2] += (wf) * lo16f(gv.y); acc[3] += (wf) * hi16f(gv.y);           \
    acc[4] += (wf) * lo16f(gv.z); acc[5] += (wf) * hi16f(gv.z);           \
    acc[6] += (wf) * lo16f(gv.w); acc[7] += (wf) * hi16f(gv.w);
#define POINT2(p00, p10, p01, p11, wp)                          \
    CORNER1(p00, lo16f(wp.x)) CORNER1(p10, hi16f(wp.x))          \
    CORNER1(p01, lo16f(wp.y)) CORNER1(p11, hi16f(wp.y))
#endif

    #pragma unroll
    for (int b4 = 0; b4 < 4; ++b4) {
        const uint4 o0 = *reinterpret_cast<const uint4*>(&s_off[g * 68 + b4 * 16 + 0]);
        const uint4 o1 = *reinterpret_cast<const uint4*>(&s_off[g * 68 + b4 * 16 + 4]);
        const uint4 o2 = *reinterpret_cast<const uint4*>(&s_off[g * 68 + b4 * 16 + 8]);
        const uint4 o3 = *reinterpret_cast<const uint4*>(&s_off[g * 68 + b4 * 16 + 12]);
        const uint2 wp0 = *reinterpret_cast<const uint2*>(&s_w[g * 34 + b4 * 8 + 0]);
        const uint2 wp1 = *reinterpret_cast<const uint2*>(&s_w[g * 34 + b4 * 8 + 2]);
        const uint2 wp2 = *reinterpret_cast<const uint2*>(&s_w[g * 34 + b4 * 8 + 4]);
        const uint2 wp3 = *reinterpret_cast<const uint2*>(&s_w[g * 34 + b4 * 8 + 6]);
        // 16 independent gathers — all issued before any consumption
        const uint4 a00 = *reinterpret_cast<const uint4*>(vbase + o0.x);
        const uint4 a10 = *reinterpret_cast<const uint4*>(vbase + o0.y);
        const uint4 a01 = *reinterpret_cast<const uint4*>(vbase + o0.z);
        const uint4 a11 = *reinterpret_cast<const uint4*>(vbase + o0.w);
        const uint4 b00 = *reinterpret_cast<const uint4*>(vbase + o1.x);
        const uint4 b10 = *reinterpret_cast<const uint4*>(vbase + o1.y);
        const uint4 b01 = *reinterpret_cast<const uint4*>(vbase + o1.z);
        const uint4 b11 = *reinterpret_cast<const uint4*>(vbase + o1.w);
        const uint4 c00 = *reinterpret_cast<const uint4*>(vbase + o2.x);
        const uint4 c10 = *reinterpret_cast<const uint4*>(vbase + o2.y);
        const uint4 c01 = *reinterpret_cast<const uint4*>(vbase + o2.z);
        const uint4 c11 = *reinterpret_cast<const uint4*>(vbase + o2.w);
        const uint4 d00 = *reinterpret_cast<const uint4*>(vbase + o3.x);
        const uint4 d10 = *reinterpret_cast<const uint4*>(vbase + o3.y);
        const uint4 d01 = *reinterpret_cast<const uint4*>(vbase + o3.z);
        const uint4 d11 = *reinterpret_cast<const uint4*>(vbase + o3.w);
        POINT2(a00, a10, a01, a11, wp0)
        POINT2(b00, b10, b01, b11, wp1)
        POINT2(c00, c10, c01, c11, wp2)
        POINT2(d00, d10, d01, d11, wp3)
    }
#undef POINT2
#if USE_DOT2
#undef CORNER2
#else
#undef CORNER1
#endif

    const int row = row0 + (g >> 3);
    if (row < MROWS) {
        uint4 o;
        o.x = (uint)f2bf(acc[0]) | ((uint)f2bf(acc[1]) << 16);
        o.y = (uint)f2bf(acc[2]) | ((uint)f2bf(acc[3]) << 16);
        o.z = (uint)f2bf(acc[4]) | ((uint)f2bf(acc[5]) << 16);
        o.w = (uint)f2bf(acc[6]) | ((uint)f2bf(acc[7]) << 16);
        *reinterpret_cast<uint4*>((char*)outb + (size_t)row * 512 + h * 64 + cq * 16) = o;
    }
}

// ---------------- fused residual + LayerNorm (one wave per 256-row) ----------------
template<bool AF32, bool WF32>
__global__ __launch_bounds__(256) void resid_ln(
    const float* __restrict__ af, const ushort* __restrict__ ab,
    const ushort* __restrict__ r,
    const float* __restrict__ g, const float* __restrict__ be,
    float* __restrict__ outf, ushort* __restrict__ outb, int M)
{
    const int lane = threadIdx.x & 63;
    const int wid  = threadIdx.x >> 6;
    const int row  = blockIdx.x * 4 + wid;
    if (row >= M) return;

    float4 va;
    if (AF32) {
        va = *(reinterpret_cast<const float4*>(af + (size_t)row * 256) + lane);
    } else {
        ushort4 ua = *(reinterpret_cast<const ushort4*>(ab + (size_t)row * 256) + lane);
        va.x = bfbits2f(ua.x); va.y = bfbits2f(ua.y);
        va.z = bfbits2f(ua.z); va.w = bfbits2f(ua.w);
    }
    ushort4 ur = *(reinterpret_cast<const ushort4*>(r + (size_t)row * 256) + lane);
    float4 v;
    v.x = va.x + bfbits2f(ur.x); v.y = va.y + bfbits2f(ur.y);
    v.z = va.z + bfbits2f(ur.z); v.w = va.w + bfbits2f(ur.w);

    float s = v.x + v.y + v.z + v.w;
    #pragma unroll
    for (int m = 1; m < 64; m <<= 1) s += __shfl_xor(s, m);
    const float mean = s * (1.f / 256.f);

    float4 d;
    d.x = v.x - mean; d.y = v.y - mean; d.z = v.z - mean; d.w = v.w - mean;
    float q = d.x * d.x + d.y * d.y + d.z * d.z + d.w * d.w;
    #pragma unroll
    for (int m = 1; m < 64; m <<= 1) q += __shfl_xor(q, m);
    const float rs = rsqrtf(q * (1.f / 256.f) + EPS_LN);

    float4 gv = *(reinterpret_cast<const float4*>(g) + lane);
    float4 bv = *(reinterpret_cast<const float4*>(be) + lane);
    float4 o;
    o.x = d.x * rs * gv.x + bv.x;
    o.y = d.y * rs * gv.y + bv.y;
    o.z = d.z * rs * gv.z + bv.z;
    o.w = d.w * rs * gv.w + bv.w;
    if (WF32) {
        *(reinterpret_cast<float4*>(outf + (size_t)row * 256) + lane) = o;
    } else {
        ushort4 h;
        h.x = f2bf(o.x); h.y = f2bf(o.y); h.z = f2bf(o.z); h.w = f2bf(o.w);
        *(reinterpret_cast<ushort4*>(outb + (size_t)row * 256) + lane) = h;
    }
}

// ---------------- launch ----------------
extern "C" void kernel_launch(void* const* d_in, const int* in_sizes, int n_in,
                              void* d_out, int out_size, void* d_ws, size_t ws_size,
                              hipStream_t stream)
{
    const float* src   = (const float*)d_in[0];
    const float* pos   = (const float*)d_in[1];
    const float* refp  = (const float*)d_in[2];
    const float* Wv    = (const float*)d_in[3];
    const float* bv    = (const float*)d_in[4];
    const float* Woff  = (const float*)d_in[5];
    const float* boff  = (const float*)d_in[6];
    const float* Wattn = (const float*)d_in[7];
    const float* battn = (const float*)d_in[8];
    const float* Wout  = (const float*)d_in[9];
    const float* bout  = (const float*)d_in[10];
    const float* W1    = (const float*)d_in[11];
    const float* b1    = (const float*)d_in[12];
    const float* W2    = (const float*)d_in[13];
    const float* b2    = (const float*)d_in[14];
    const float* g1    = (const float*)d_in[15];
    const float* be1   = (const float*)d_in[16];
    const float* g2    = (const float*)d_in[17];
    const float* be2   = (const float*)d_in[18];
    float* out = (float*)d_out;

    // ---------------- workspace layout (bytes) ----------------
    // hb in [0, 4SB): srcb/qb/valueb/oab all dead before FFN1; disjoint from x1b/ffnb.
    char* wsb = (char*)d_ws;
    const size_t SB   = (size_t)PADM * 256 * 2;    // 13,631,488
    const size_t OABS = (size_t)PADM * 384 * 2;    // 20,447,232
    ushort* srcb   = (ushort*)(wsb);                    // [0, SB)
    ushort* qb     = (ushort*)(wsb + SB);               // [SB, 2SB)
    ushort* valueb = (ushort*)(wsb + 2 * SB);           // [2SB, 3SB)
    ushort* oab    = (ushort*)(wsb + 3 * SB);           // [3SB, 3SB+OABS)
    ushort* attnb  = (ushort*)(wsb + 3 * SB + OABS);    // [.., +SB)
    ushort* src2b  = (ushort*)(wsb + 4 * SB + OABS);    // later: ffnb
    ushort* ffnb   = src2b;
    ushort* x1b    = (ushort*)(wsb + 5 * SB + OABS);
    ushort* hb     = (ushort*)(wsb);                    // [0, 4SB)
    char*   wgt    = wsb + 6 * SB + OABS;               // ~102.2 MB
    ushort* wvt    = (ushort*)(wgt);                    // 256x256
    ushort* woat   = (ushort*)(wgt + 131072);           // 384x256
    ushort* woutt  = (ushort*)(wgt + 327680);           // 256x256
    ushort* w1t    = (ushort*)(wgt + 458752);           // 1024x256
    ushort* w2t    = (ushort*)(wgt + 983040);           // 256x1024

    const dim3 blk(256);

    // weights convert+transpose + src/q bf16 (one kernel)
    prep_all<<<dim3(736 + PADM / 4), blk, 0, stream>>>(
        Wv, Woff, Wattn, Wout, W1, W2, wvt, woat, woutt, w1t, w2t,
        src, pos, srcb, qb);

    // value = src @ Wv + bv  AND  [off|logits] = (src+pos) @ [Woff|Wattn] + bias
    gemm_pair<<<dim3(416 * 5), blk, 0, stream>>>(
        srcb, wvt, bv, valueb, qb, woat, boff, battn, oab);

    // deformable sampling (softmax fused); 8 rows/block
    ms_sample<<<dim3(3324), blk, 0, stream>>>(valueb, oab, refp, attnb);

    // src2 = attn @ Wout + bout
    gemm_single<2, 2, false><<<dim3(416 * 2), blk, 0, stream>>>(
        attnb, woutt, bout, bout, 256, src2b, 256, 256);

    // x1 = LN(src + src2) -> x1b (bf16); src read fp32 (accuracy margin)
    resid_ln<true, false><<<dim3(6647), blk, 0, stream>>>(
        src, nullptr, src2b, g1, be1, nullptr, x1b, MROWS);

    // h = relu(x1 @ W1 + b1) -> hb
    gemm_single<4, 8, true><<<dim3(208 * 8), blk, 0, stream>>>(
        x1b, w1t, b1, b1, 1024, hb, 1024, 256);

    // ffn = h @ W2 + b2
    gemm_single<2, 2, false><<<dim3(416 * 2), blk, 0, stream>>>(
        hb, w2t, b2, b2, 256, ffnb, 256, 1024);

    // out = LN(x1 + ffn) -> d_out (fp32)
    resid_ln<false, true><<<dim3(6647), blk, 0, stream>>>(
        nullptr, x1b, ffnb, g2, be2, out, nullptr, MROWS);
}

// Round 14
// 165.502 us; speedup vs baseline: 1.5003x; 1.5003x over previous
//
#include <hip/hip_runtime.h>
#include <hip/hip_bf16.h>

// ---------------- problem constants ----------------
#define LENQ 13294
#define MROWS 26588              // 2 * LENQ
#define PADM  26624              // 416 * 64 = 208 * 128
#define EPS_LN 1e-5f

typedef __attribute__((ext_vector_type(8))) short short8;
typedef __attribute__((ext_vector_type(4))) float vf4;
typedef __attribute__((ext_vector_type(2))) __bf16 bf16x2;

__device__ inline ushort f2bf(float f) {
    __hip_bfloat16 h = __float2bfloat16(f);
    return reinterpret_cast<ushort&>(h);
}
__device__ inline float bfbits2f(uint lo16) { return __uint_as_float(lo16 << 16); }
__device__ inline float lo16f(uint u) { return __uint_as_float(u << 16); }
__device__ inline float hi16f(uint u) { return __uint_as_float(u & 0xffff0000u); }

#if __has_builtin(__builtin_amdgcn_fdot2_f32_bf16) && __has_builtin(__builtin_amdgcn_perm)
#define USE_DOT2 1
__device__ inline bf16x2 u2bf2(uint u) { return __builtin_bit_cast(bf16x2, u); }
#define SEL_EVEN 0x01000504u
#define SEL_ODD  0x03020706u
#else
#define USE_DOT2 0
#endif

// async global->LDS, 16B per lane; LDS dest is wave-uniform base + lane*16
__device__ inline void load_lds16(const void* g, void* l) {
    __builtin_amdgcn_global_load_lds(
        (const __attribute__((address_space(1))) unsigned int*)g,
        (__attribute__((address_space(3))) unsigned int*)l,
        16, 0, 0);
}

// XCD-grouping block decode: all NT n-tiles of one m-panel land on the SAME XCD
// (bid % 8 == mt % 8 constant within the group) and are temporally adjacent,
// so the A-panel is fetched into that XCD's L2 once instead of NT times.
// Bijective when MT % 8 == 0.  [validated round 11: ~12 us on the GEMM cluster]
__device__ inline void xcd_decode(int bid, int NT, int& mt, int& nt) {
    const int xcd = bid & 7;
    const int rest = bid >> 3;
    nt = rest % NT;
    mt = (rest / NT) * 8 + xcd;
}

// ---------------- fused prep: all-weights convert+transpose AND src/q bf16 ----------------
__global__ __launch_bounds__(256) void prep_all(
    const float* __restrict__ Wv, const float* __restrict__ Woff,
    const float* __restrict__ Wattn, const float* __restrict__ Wout,
    const float* __restrict__ W1, const float* __restrict__ W2,
    ushort* __restrict__ wvt, ushort* __restrict__ woat,
    ushort* __restrict__ woutt, ushort* __restrict__ w1t, ushort* __restrict__ w2t,
    const float* __restrict__ srcf, const float* __restrict__ posf,
    ushort* __restrict__ srcb, ushort* __restrict__ qb)
{
    __shared__ float s[32][36];
    const int bid = blockIdx.x;
    const int t = threadIdx.x;
    if (bid < 736) {
        const float* src; ushort* dst; int K, N, tb;
        if      (bid < 64)  { src = Wv;    dst = wvt;            K = 256;  N = 256;  tb = bid; }
        else if (bid < 128) { src = Woff;  dst = woat;           K = 256;  N = 256;  tb = bid - 64; }
        else if (bid < 160) { src = Wattn; dst = woat + 256*256; K = 256;  N = 128;  tb = bid - 128; }
        else if (bid < 224) { src = Wout;  dst = woutt;          K = 256;  N = 256;  tb = bid - 160; }
        else if (bid < 480) { src = W1;    dst = w1t;            K = 256;  N = 1024; tb = bid - 224; }
        else                { src = W2;    dst = w2t;            K = 1024; N = 256;  tb = bid - 480; }
        const int ntn = N >> 5;
        const int kt = tb / ntn, nt = tb % ntn;
        const int ty = t >> 3, tx = (t & 7) * 4;
        float4 v = *reinterpret_cast<const float4*>(src + (size_t)(kt*32 + ty) * N + nt*32 + tx);
        s[ty][tx+0] = v.x; s[ty][tx+1] = v.y; s[ty][tx+2] = v.z; s[ty][tx+3] = v.w;
        __syncthreads();
        ushort4 o;
        o.x = f2bf(s[tx+0][ty]); o.y = f2bf(s[tx+1][ty]);
        o.z = f2bf(s[tx+2][ty]); o.w = f2bf(s[tx+3][ty]);
        *reinterpret_cast<ushort4*>(dst + (size_t)(nt*32 + ty) * K + kt*32 + tx) = o;
    } else {
        const int i = (bid - 736) * 256 + t;       // float4 index over PADM*64
        const int row = i >> 6;
        const int c4 = i & 63;
        const int sr = min(row, MROWS - 1);
        float4 sv = reinterpret_cast<const float4*>(srcf)[(size_t)sr * 64 + c4];
        float4 pv = reinterpret_cast<const float4*>(posf)[(size_t)sr * 64 + c4];
        ushort4 sb, qv;
        sb.x = f2bf(sv.x); sb.y = f2bf(sv.y); sb.z = f2bf(sv.z); sb.w = f2bf(sv.w);
        qv.x = f2bf(sv.x + pv.x); qv.y = f2bf(sv.y + pv.y);
        qv.z = f2bf(sv.z + pv.z); qv.w = f2bf(sv.w + pv.w);
        reinterpret_cast<ushort4*>(srcb)[(size_t)row * 64 + c4] = sb;
        reinterpret_cast<ushort4*>(qb)[(size_t)row * 64 + c4]   = qv;
    }
}

// ---------------- m97-style bf16 MFMA GEMM body, 2-phase prefetch (double-buffered) ----
// Tile BM x 128 (BM = MF*32), BK=32, 4 waves (2x2), global_load_lds staging.
template<int MF, bool RELU>
__device__ __forceinline__ void gemm_body(
    const ushort* __restrict__ A, const ushort* __restrict__ Bt,
    const float* __restrict__ bias0, const float* __restrict__ bias1, int nsplit,
    ushort* __restrict__ C, int N, int K, int m0, int n0,
    short* AsP, short* BsP)
{
    constexpr int BM = MF * 32;
    const int t = threadIdx.x;
    const int lane = t & 63, w = t >> 6;
    const int wr = w >> 1, wc = w & 1;
    const int ln = lane & 15, lr = lane >> 4;
    const int swz = (lr ^ ((ln >> 1) & 3)) * 8;
    const int cg = (((lane & 3) ^ ((lane >> 3) & 3))) * 8;
    const int srow = lane >> 2;

    vf4 acc[MF][4];
    #pragma unroll
    for (int m = 0; m < MF; ++m)
        #pragma unroll
        for (int n = 0; n < 4; ++n)
            acc[m][n] = (vf4){0.f, 0.f, 0.f, 0.f};

    const int ach0 = (MF == 4) ? 2 * w : w;
    const ushort* gA0 = A + (size_t)(m0 + ach0 * 16 + srow) * K + cg;
    const ushort* gA1 = A + (size_t)(m0 + (2 * w + 1) * 16 + srow) * K + cg;  // MF==4
    const ushort* gB0 = Bt + (size_t)(n0 + (2 * w) * 16 + srow) * K + cg;
    const ushort* gB1 = Bt + (size_t)(n0 + (2 * w + 1) * 16 + srow) * K + cg;
    const int lA0 = ach0 * 512, lA1 = (2 * w + 1) * 512;
    const int lB0 = (2 * w) * 512, lB1 = (2 * w + 1) * 512;

#define STAGE_TILE(buf, kk) do {                                              \
        load_lds16(gA0 + (kk), AsP + (buf) * (BM * 32) + lA0);                \
        if constexpr (MF == 4) load_lds16(gA1 + (kk), AsP + (buf) * (BM * 32) + lA1); \
        load_lds16(gB0 + (kk), BsP + (buf) * (128 * 32) + lB0);               \
        load_lds16(gB1 + (kk), BsP + (buf) * (128 * 32) + lB1);               \
    } while (0)

    STAGE_TILE(0, 0);
    int cur = 0;
    for (int k0 = 0; k0 < K; k0 += 32) {
        __syncthreads();
        if (k0 + 32 < K) STAGE_TILE(cur ^ 1, k0 + 32);

        short8 af[MF], bfr[4];
        #pragma unroll
        for (int m = 0; m < MF; ++m)
            af[m] = *reinterpret_cast<const short8*>(
                AsP + cur * (BM * 32) + (wr * (MF * 16) + m * 16 + ln) * 32 + swz);
        #pragma unroll
        for (int n = 0; n < 4; ++n)
            bfr[n] = *reinterpret_cast<const short8*>(
                BsP + cur * (128 * 32) + (wc * 64 + n * 16 + ln) * 32 + swz);
        #pragma unroll
        for (int m = 0; m < MF; ++m)
            #pragma unroll
            for (int n = 0; n < 4; ++n)
                acc[m][n] = __builtin_amdgcn_mfma_f32_16x16x32_bf16(af[m], bfr[n], acc[m][n], 0, 0, 0);
        cur ^= 1;
    }
#undef STAGE_TILE

    #pragma unroll
    for (int n = 0; n < 4; ++n) {
        const int col = n0 + wc * 64 + n * 16 + ln;
        const float b = (col < nsplit) ? bias0[col] : bias1[col - nsplit];
        #pragma unroll
        for (int m = 0; m < MF; ++m) {
            const int rbase = m0 + wr * (MF * 16) + m * 16 + lr * 4;
            #pragma unroll
            for (int q = 0; q < 4; ++q) {
                float v = acc[m][n][q] + b;
                if (RELU) v = fmaxf(v, 0.f);
                C[(size_t)(rbase + q) * N + col] = f2bf(v);
            }
        }
    }
}

// 1D grid, XCD-grouped; grid = (PADM/BM) * NT blocks
template<int MF, int NT, bool RELU>
__global__ __launch_bounds__(256) void gemm_single(
    const ushort* __restrict__ A, const ushort* __restrict__ Bt,
    const float* __restrict__ bias0, const float* __restrict__ bias1, int nsplit,
    ushort* __restrict__ C, int N, int K)
{
    constexpr int BM = MF * 32;
    __shared__ short As[2 * BM * 32];
    __shared__ short Bs[2 * 128 * 32];
    int mt, nt;
    xcd_decode(blockIdx.x, NT, mt, nt);
    gemm_body<MF, RELU>(A, Bt, bias0, bias1, nsplit, C, N, K,
                        mt * BM, nt * 128, As, Bs);
}

// value GEMM (nt<2) and [off|attn] GEMM (nt>=2) in one 1D launch, XCD-grouped (NT=5)
__global__ __launch_bounds__(256) void gemm_pair(
    const ushort* __restrict__ srcb, const ushort* __restrict__ wvt,
    const float* __restrict__ bv, ushort* __restrict__ valueb,
    const ushort* __restrict__ qb, const ushort* __restrict__ woat,
    const float* __restrict__ boff, const float* __restrict__ battn,
    ushort* __restrict__ oab)
{
    __shared__ short As[2 * 64 * 32];
    __shared__ short Bs[2 * 128 * 32];
    int mt, nt;
    xcd_decode(blockIdx.x, 5, mt, nt);
    if (nt < 2) {
        gemm_body<2, false>(srcb, wvt, bv, bv, 256, valueb, 256, 256,
                            mt * 64, nt * 128, As, Bs);
    } else {
        gemm_body<2, false>(qb, woat, boff, battn, 256, oab, 384, 256,
                            mt * 64, (nt - 2) * 128, As, Bs);
    }
}

// ---------------- fused softmax + multi-scale deformable sampling (bf16) ----------------
// 8 rows/block (round-8/11 form — the measured optimum; r9/r10/r12/r13 perturbations all
// regressed). Phase 1: per (r,h,lp) -> 4 byte-offsets + 2 bf16-pair weights -> LDS (SoA).
// Phase 2: 4 threads per (r,h), 8 channels each; dot2, one point (4 gathers) per iter.
__global__ __launch_bounds__(256) void ms_sample(
    const ushort* __restrict__ value, const ushort* __restrict__ oa,
    const float* __restrict__ ref, ushort* __restrict__ outb)
{
    __shared__ uint s_off[64 * 68];   // 17408 B, group stride 68 uints
    __shared__ uint s_w[64 * 34];     // 8704 B, group stride 34 uints

    const int t    = threadIdx.x;
    const int row0 = blockIdx.x * 8;

    #pragma unroll
    for (int j = 0; j < 4; ++j) {
        const int item = t + j * 256;          // 0..1023
        const int r = item >> 7, h = (item >> 4) & 7, lp = item & 15;
        const int l = lp >> 2;
        const int row = min(row0 + r, MROWS - 1);
        const int bsel = (row >= LENQ) ? 1 : 0;

        const float lg = bfbits2f(oa[(size_t)row * 384 + 256 + h * 16 + lp]);
        float mx = lg;
        #pragma unroll
        for (int s2 = 1; s2 < 16; s2 <<= 1) mx = fmaxf(mx, __shfl_xor(mx, s2));
        const float e = __expf(lg - mx);
        float se = e;
        #pragma unroll
        for (int s2 = 1; s2 < 16; s2 <<= 1) se += __shfl_xor(se, s2);
        const float aw = e / se;

        const int W = (int)((0x0D193264u >> (l * 8)) & 0xffu);   // 100,50,25,13
        const int LS = (l == 0) ? 0 : (l == 1) ? 10000 : (l == 2) ? 12500 : 13125;
        const uint oxy = *reinterpret_cast<const uint*>(oa + (size_t)row * 384 + (h * 16 + lp) * 2);
        const float ox = lo16f(oxy);
        const float oy = hi16f(oxy);
        const float rx = ref[(size_t)row * 8 + l * 2 + 0];
        const float ry = ref[(size_t)row * 8 + l * 2 + 1];
        const float fw = (float)W;
        const float x = (rx + ox / fw) * fw - 0.5f;
        const float y = (ry + oy / fw) * fw - 0.5f;
        const float fx = floorf(x), fy = floorf(y);
        const float dx = x - fx, dy = y - fy;
        const int x0 = (int)fx, y0 = (int)fy;
        const int x1i = x0 + 1, y1i = y0 + 1;
        const int gbase = bsel * LENQ + LS;

        const bool inx0 = (x0 >= 0) && (x0 < W), inx1 = (x1i >= 0) && (x1i < W);
        const bool iny0 = (y0 >= 0) && (y0 < W), iny1 = (y1i >= 0) && (y1i < W);
        const int xc0 = min(max(x0, 0), W - 1), xc1 = min(max(x1i, 0), W - 1);
        const int yc0 = min(max(y0, 0), W - 1), yc1 = min(max(y1i, 0), W - 1);
        const float w00 = (inx0 && iny0) ? (1.f - dx) * (1.f - dy) * aw : 0.f;
        const float w10 = (inx1 && iny0) ? dx * (1.f - dy) * aw : 0.f;
        const float w01 = (inx0 && iny1) ? (1.f - dx) * dy * aw : 0.f;
        const float w11 = (inx1 && iny1) ? dx * dy * aw : 0.f;
        const uint b0 = (uint)(gbase + yc0 * W);
        const uint b1 = (uint)(gbase + yc1 * W);
        const int g = r * 8 + h;
        *reinterpret_cast<uint4*>(&s_off[g * 68 + lp * 4]) =
            make_uint4((b0 + (uint)xc0) * 512u, (b0 + (uint)xc1) * 512u,
                       (b1 + (uint)xc0) * 512u, (b1 + (uint)xc1) * 512u);
        const uint wA = (uint)f2bf(w00) | ((uint)f2bf(w10) << 16);
        const uint wB = (uint)f2bf(w01) | ((uint)f2bf(w11) << 16);
        *reinterpret_cast<uint2*>(&s_w[g * 34 + lp * 2]) = make_uint2(wA, wB);
    }
    __syncthreads();

    // phase 2: 4 threads per (r,h) group, 8 bf16 channels per thread
    const int g = t >> 2, cq = t & 3;
    const int h = g & 7;
    const char* vbase = (const char*)value + h * 64 + cq * 16;
    float acc[8] = {0.f, 0.f, 0.f, 0.f, 0.f, 0.f, 0.f, 0.f};
    #pragma unroll 2
    for (int pt = 0; pt < 16; ++pt) {
        const uint4 o4 = *reinterpret_cast<const uint4*>(&s_off[g * 68 + pt * 4]);
        const uint2 wp = *reinterpret_cast<const uint2*>(&s_w[g * 34 + pt * 2]);
        const uint4 g00 = *reinterpret_cast<const uint4*>(vbase + o4.x);
        const uint4 g10 = *reinterpret_cast<const uint4*>(vbase + o4.y);
        const uint4 g01 = *reinterpret_cast<const uint4*>(vbase + o4.z);
        const uint4 g11 = *reinterpret_cast<const uint4*>(vbase + o4.w);
#if USE_DOT2
#define CORNER2(u0, u1, wpk, klo, khi)                                                 \
        acc[klo] = __builtin_amdgcn_fdot2_f32_bf16(                                    \
            u2bf2(__builtin_amdgcn_perm((u0), (u1), SEL_EVEN)), u2bf2(wpk), acc[klo], false); \
        acc[khi] = __builtin_amdgcn_fdot2_f32_bf16(                                    \
            u2bf2(__builtin_amdgcn_perm((u0), (u1), SEL_ODD)),  u2bf2(wpk), acc[khi], false);
        CORNER2(g00.x, g10.x, wp.x, 0, 1) CORNER2(g01.x, g11.x, wp.y, 0, 1)
        CORNER2(g00.y, g10.y, wp.x, 2, 3) CORNER2(g01.y, g11.y, wp.y, 2, 3)
        CORNER2(g00.z, g10.z, wp.x, 4, 5) CORNER2(g01.z, g11.z, wp.y, 4, 5)
        CORNER2(g00.w, g10.w, wp.x, 6, 7) CORNER2(g01.w, g11.w, wp.y, 6, 7)
#undef CORNER2
#else
        const float w00f = lo16f(wp.x), w10f = hi16f(wp.x);
        const float w01f = lo16f(wp.y), w11f = hi16f(wp.y);
#define CORNER1(gv, wf)                                                   \
        acc[0] += (wf) * lo16f(gv.x); acc[1] += (wf) * hi16f(gv.x);       \
        acc[2] += (wf) * lo16f(gv.y); acc[3] += (wf) * hi16f(gv.y);       \
        acc[4] += (wf) * lo16f(gv.z); acc[5] += (wf) * hi16f(gv.z);       \
        acc[6] += (wf) * lo16f(gv.w); acc[7] += (wf) * hi16f(gv.w);
        CORNER1(g00, w00f) CORNER1(g10, w10f) CORNER1(g01, w01f) CORNER1(g11, w11f)
#undef CORNER1
#endif
    }
    const int row = row0 + (g >> 3);
    if (row < MROWS) {
        uint4 o;
        o.x = (uint)f2bf(acc[0]) | ((uint)f2bf(acc[1]) << 16);
        o.y = (uint)f2bf(acc[2]) | ((uint)f2bf(acc[3]) << 16);
        o.z = (uint)f2bf(acc[4]) | ((uint)f2bf(acc[5]) << 16);
        o.w = (uint)f2bf(acc[6]) | ((uint)f2bf(acc[7]) << 16);
        *reinterpret_cast<uint4*>((char*)outb + (size_t)row * 512 + h * 64 + cq * 16) = o;
    }
}

// ---------------- fused residual + LayerNorm (one wave per 256-row) ----------------
template<bool AF32, bool WF32>
__global__ __launch_bounds__(256) void resid_ln(
    const float* __restrict__ af, const ushort* __restrict__ ab,
    const ushort* __restrict__ r,
    const float* __restrict__ g, const float* __restrict__ be,
    float* __restrict__ outf, ushort* __restrict__ outb, int M)
{
    const int lane = threadIdx.x & 63;
    const int wid  = threadIdx.x >> 6;
    const int row  = blockIdx.x * 4 + wid;
    if (row >= M) return;

    float4 va;
    if (AF32) {
        va = *(reinterpret_cast<const float4*>(af + (size_t)row * 256) + lane);
    } else {
        ushort4 ua = *(reinterpret_cast<const ushort4*>(ab + (size_t)row * 256) + lane);
        va.x = bfbits2f(ua.x); va.y = bfbits2f(ua.y);
        va.z = bfbits2f(ua.z); va.w = bfbits2f(ua.w);
    }
    ushort4 ur = *(reinterpret_cast<const ushort4*>(r + (size_t)row * 256) + lane);
    float4 v;
    v.x = va.x + bfbits2f(ur.x); v.y = va.y + bfbits2f(ur.y);
    v.z = va.z + bfbits2f(ur.z); v.w = va.w + bfbits2f(ur.w);

    float s = v.x + v.y + v.z + v.w;
    #pragma unroll
    for (int m = 1; m < 64; m <<= 1) s += __shfl_xor(s, m);
    const float mean = s * (1.f / 256.f);

    float4 d;
    d.x = v.x - mean; d.y = v.y - mean; d.z = v.z - mean; d.w = v.w - mean;
    float q = d.x * d.x + d.y * d.y + d.z * d.z + d.w * d.w;
    #pragma unroll
    for (int m = 1; m < 64; m <<= 1) q += __shfl_xor(q, m);
    const float rs = rsqrtf(q * (1.f / 256.f) + EPS_LN);

    float4 gv = *(reinterpret_cast<const float4*>(g) + lane);
    float4 bv = *(reinterpret_cast<const float4*>(be) + lane);
    float4 o;
    o.x = d.x * rs * gv.x + bv.x;
    o.y = d.y * rs * gv.y + bv.y;
    o.z = d.z * rs * gv.z + bv.z;
    o.w = d.w * rs * gv.w + bv.w;
    if (WF32) {
        *(reinterpret_cast<float4*>(outf + (size_t)row * 256) + lane) = o;
    } else {
        ushort4 h;
        h.x = f2bf(o.x); h.y = f2bf(o.y); h.z = f2bf(o.z); h.w = f2bf(o.w);
        *(reinterpret_cast<ushort4*>(outb + (size_t)row * 256) + lane) = h;
    }
}

// ---------------- launch ----------------
extern "C" void kernel_launch(void* const* d_in, const int* in_sizes, int n_in,
                              void* d_out, int out_size, void* d_ws, size_t ws_size,
                              hipStream_t stream)
{
    const float* src   = (const float*)d_in[0];
    const float* pos   = (const float*)d_in[1];
    const float* refp  = (const float*)d_in[2];
    const float* Wv    = (const float*)d_in[3];
    const float* bv    = (const float*)d_in[4];
    const float* Woff  = (const float*)d_in[5];
    const float* boff  = (const float*)d_in[6];
    const float* Wattn = (const float*)d_in[7];
    const float* battn = (const float*)d_in[8];
    const float* Wout  = (const float*)d_in[9];
    const float* bout  = (const float*)d_in[10];
    const float* W1    = (const float*)d_in[11];
    const float* b1    = (const float*)d_in[12];
    const float* W2    = (const float*)d_in[13];
    const float* b2    = (const float*)d_in[14];
    const float* g1    = (const float*)d_in[15];
    const float* be1   = (const float*)d_in[16];
    const float* g2    = (const float*)d_in[17];
    const float* be2   = (const float*)d_in[18];
    float* out = (float*)d_out;

    // ---------------- workspace layout (bytes) ----------------
    // hb in [0, 4SB): srcb/qb/valueb/oab all dead before FFN1 (srcb's last reader is
    // LN1, which precedes FFN1); disjoint from x1b/ffnb.
    char* wsb = (char*)d_ws;
    const size_t SB   = (size_t)PADM * 256 * 2;    // 13,631,488
    const size_t OABS = (size_t)PADM * 384 * 2;    // 20,447,232
    ushort* srcb   = (ushort*)(wsb);                    // [0, SB)
    ushort* qb     = (ushort*)(wsb + SB);               // [SB, 2SB)
    ushort* valueb = (ushort*)(wsb + 2 * SB);           // [2SB, 3SB)
    ushort* oab    = (ushort*)(wsb + 3 * SB);           // [3SB, 3SB+OABS)
    ushort* attnb  = (ushort*)(wsb + 3 * SB + OABS);    // [.., +SB)
    ushort* src2b  = (ushort*)(wsb + 4 * SB + OABS);    // later: ffnb
    ushort* ffnb   = src2b;
    ushort* x1b    = (ushort*)(wsb + 5 * SB + OABS);
    ushort* hb     = (ushort*)(wsb);                    // [0, 4SB)
    char*   wgt    = wsb + 6 * SB + OABS;               // ~102.2 MB
    ushort* wvt    = (ushort*)(wgt);                    // 256x256
    ushort* woat   = (ushort*)(wgt + 131072);           // 384x256
    ushort* woutt  = (ushort*)(wgt + 327680);           // 256x256
    ushort* w1t    = (ushort*)(wgt + 458752);           // 1024x256
    ushort* w2t    = (ushort*)(wgt + 983040);           // 256x1024

    const dim3 blk(256);

    // weights convert+transpose + src/q bf16 (one kernel)
    prep_all<<<dim3(736 + PADM / 4), blk, 0, stream>>>(
        Wv, Woff, Wattn, Wout, W1, W2, wvt, woat, woutt, w1t, w2t,
        src, pos, srcb, qb);

    // value = src @ Wv + bv  AND  [off|logits] = (src+pos) @ [Woff|Wattn] + bias
    gemm_pair<<<dim3(416 * 5), blk, 0, stream>>>(
        srcb, wvt, bv, valueb, qb, woat, boff, battn, oab);

    // deformable sampling (softmax fused); 8 rows/block
    ms_sample<<<dim3(3324), blk, 0, stream>>>(valueb, oab, refp, attnb);

    // src2 = attn @ Wout + bout
    gemm_single<2, 2, false><<<dim3(416 * 2), blk, 0, stream>>>(
        attnb, woutt, bout, bout, 256, src2b, 256, 256);

    // x1 = LN(src + src2) -> x1b (bf16); src read as bf16 srcb (validated round 5,
    // same absmax 0.03125; saves 13.6 MB vs fp32 src read)
    resid_ln<false, false><<<dim3(6647), blk, 0, stream>>>(
        nullptr, srcb, src2b, g1, be1, nullptr, x1b, MROWS);

    // h = relu(x1 @ W1 + b1) -> hb
    gemm_single<4, 8, true><<<dim3(208 * 8), blk, 0, stream>>>(
        x1b, w1t, b1, b1, 1024, hb, 1024, 256);

    // ffn = h @ W2 + b2
    gemm_single<2, 2, false><<<dim3(416 * 2), blk, 0, stream>>>(
        hb, w2t, b2, b2, 256, ffnb, 256, 1024);

    // out = LN(x1 + ffn) -> d_out (fp32)
    resid_ln<false, true><<<dim3(6647), blk, 0, stream>>>(
        nullptr, x1b, ffnb, g2, be2, out, nullptr, MROWS);
}